// Round 11
// baseline (263.443 us; speedup 1.0000x reference)
//
#include <hip/hip_runtime.h>
#include <hip/hip_bf16.h>

typedef __attribute__((ext_vector_type(8))) short short8;
typedef __attribute__((ext_vector_type(16))) float floatx16;

#define BDIM 256

constexpr int kCIN = 256, kCOUT = 256, kH = 64, kW = 64;
constexpr int BK = 32;                  // ci per chunk
constexpr int NCHUNK = kCIN / BK;       // 8
constexpr int ROWS = 4;                 // output rows per block
constexpr int XR = ROWS + 2, XC = 66, NPIX = XR * XC;  // 396 halo pixels
constexpr int HW = kH * kW;
constexpr int GROUPS = NCHUNK * 3;      // 24 (group = one kh row of taps)

// K-major LDS layouts (contiguous per 32-lane half => conflict-free):
//   xs: [buf2][g=0..3][pix][16B]   ws: [buf2][tap j=0..2][g=0..3][co][16B]
constexpr int XS_PLANE = NPIX * 16;
constexpr int XS_BUF   = 4 * XS_PLANE;   // 25.3 KB
constexpr int WS_PLANE = 256 * 16;
constexpr int WS_TILE  = 4 * WS_PLANE;   // 16 KB
constexpr int WS_GRP   = 3 * WS_TILE;    // 48 KB
// total LDS 145.5 KB -> 1 block/CU (deliberate: 1 wave/SIMD, ILP regime)

__device__ __forceinline__ unsigned short f2bf(float f) {
    unsigned u = __float_as_uint(f);
    u += 0x7fffu + ((u >> 16) & 1u);   // RNE
    return (unsigned short)(u >> 16);
}

// weight[co][ci][kh][kw] fp32 -> wt2[kk][chunk][g][co][j] bf16 (ci=chunk*32+g*8+j)
__global__ void wt_transform_kernel(const float* __restrict__ wsrc,
                                    unsigned short* __restrict__ wt2) {
    int idx = blockIdx.x * 256 + threadIdx.x;
    if (idx >= 9 * 256 * 256) return;
    int j  = idx & 7;
    int co = (idx >> 3) & 255;
    int g  = (idx >> 11) & 3;
    int chunk = (idx >> 13) & 7;
    int kk = idx >> 16;
    int ci = chunk * 32 + g * 8 + j;
    wt2[idx] = f2bf(wsrc[(co * 256 + ci) * 9 + kk]);
}

// Block: 256 cout x 256 pixels (4 rows). 4 waves = 2(co-group) x 2(row-pair).
// Wave tile: 128 co x 128 pix -> acc 4x4 frags (256 regs), 16 ds_reads feed
// 32 MFMAs per tap (0.5 reads/MFMA — best LDS economy). 1 wave/SIMD: the
// ~130 spare VGPRs let the compiler pipeline next-tap reads + x staging
// under the 1024-cyc MFMA bursts (ILP instead of TLP).
__global__ __launch_bounds__(BDIM, 1)
void conv3x3_mfma_kernel(const float* __restrict__ x,
                         const unsigned short* __restrict__ wt2,
                         const float* __restrict__ bias,
                         float* __restrict__ out) {
    __shared__ __align__(16) char xs[2 * XS_BUF];   // 50.7 KB
    __shared__ __align__(16) char ws[2 * WS_GRP];   // 96 KB

    const int bid = blockIdx.x;
    const int b  = bid >> 4;            // 16 h-tiles per image
    const int h0 = (bid & 15) * ROWS;

    const int tid = threadIdx.x;
    const int wv  = tid >> 6;           // 0..3
    const int l   = tid & 63;
    const int l31 = l & 31;
    const int hi2 = l >> 5;
    const int cog   = (wv & 1) * 128;   // wave's cout base (0/128)
    const int wrow0 = (wv >> 1) * 2;    // wave's first output row (0/2)

    const float* xb = x + (size_t)b * kCIN * HW;

    floatx16 acc[4][4] = {};            // [co frag][pix frag]

    // Stage the 3 W tiles of group grp (chunk=grp/3, kh=grp%3) into buf grp&1.
    // 12 global_load_lds per wave per group; per-lane global src contiguous.
    auto stageW3 = [&](int grp) {
        int chunk = grp / 3, kh = grp % 3;
        char* gbuf = ws + (grp & 1) * WS_GRP;
        #pragma unroll
        for (int j = 0; j < 3; ++j) {
            int kk = kh * 3 + j;
            const unsigned short* wp = wt2 + (size_t)(kk * 8 + chunk) * 8192;
            char* wbuf = gbuf + j * WS_TILE;
            #pragma unroll
            for (int it = 0; it < 4; ++it) {
                int c = wv * 4 + it;     // 0..15
                int g = c >> 2;
                int row0 = (c & 3) * 64;
                const unsigned short* src = wp + (g * 256 + row0 + l) * 8;
                __builtin_amdgcn_global_load_lds(
                    (const __attribute__((address_space(1))) unsigned int*)src,
                    (__attribute__((address_space(3))) unsigned int*)
                        (wbuf + g * WS_PLANE + row0 * 16),
                    16, 0, 0);
            }
        }
    };

    // x halo staging: rows h0-1..h0+ROWS, cols -1..64, 32 ci, fp32->bf16
    auto stageX = [&](int chunk) {
        char* xbuf = xs + (chunk & 1) * XS_BUF;
        const int ci0 = chunk * BK;
        #pragma unroll
        for (int it = 0; it < 7; ++it) {
            int t = tid + it * BDIM;
            if (it < 6 || t < NPIX * 4) {
                int g = t / NPIX;
                int rem = t - g * NPIX;
                int r = rem / XC;
                int c = rem - r * XC;
                int ih = h0 - 1 + r;
                int iw = c - 1;
                float v[8];
                if ((unsigned)ih < (unsigned)kH && (unsigned)iw < (unsigned)kW) {
                    const float* p = xb + (size_t)(ci0 + g * 8) * HW + ih * kW + iw;
                    #pragma unroll
                    for (int j = 0; j < 8; ++j) v[j] = p[(size_t)j * HW];
                } else {
                    #pragma unroll
                    for (int j = 0; j < 8; ++j) v[j] = 0.f;
                }
                union { short8 s8; unsigned short u[8]; } pk;
                #pragma unroll
                for (int j = 0; j < 8; ++j) pk.u[j] = f2bf(v[j]);
                int pix = r * XC + c;
                *(short8*)(xbuf + g * XS_PLANE + pix * 16) = pk.s8;
            }
        }
    };

    stageX(0);
    stageW3(0);
    __syncthreads();                    // prologue drain (once)

    #pragma unroll 1
    for (int grp = 0; grp < GROUPS; ++grp) {
        const int chunk = grp / 3;
        const int kh = grp % 3;

        if (grp + 1 < GROUPS) stageW3(grp + 1);           // fire-and-forget DMA
        if (kh == 0 && chunk + 1 < NCHUNK) stageX(chunk + 1);  // 3 groups early

        const char* gbuf = ws + (grp & 1) * WS_GRP;
        const char* xbuf = xs + (chunk & 1) * XS_BUF;

        #pragma unroll
        for (int kwo = 0; kwo < 3; ++kwo) {
            const char* wbuf = gbuf + kwo * WS_TILE;
            short8 a[2][4], bfr[2][4];
            #pragma unroll
            for (int s = 0; s < 2; ++s) {
                const int g = s * 2 + hi2;
                #pragma unroll
                for (int i = 0; i < 4; ++i) {
                    int co = cog + i * 32 + l31;
                    a[s][i] = *(const short8*)(wbuf + g * WS_PLANE + co * 16);
                }
                #pragma unroll
                for (int f = 0; f < 4; ++f) {
                    int r = wrow0 + (f >> 1) + kh;
                    int pix = r * XC + (f & 1) * 32 + l31 + kwo;
                    bfr[s][f] = *(const short8*)(xbuf + g * XS_PLANE + pix * 16);
                }
            }
            #pragma unroll
            for (int s = 0; s < 2; ++s)
                #pragma unroll
                for (int i = 0; i < 4; ++i)
                    #pragma unroll
                    for (int f = 0; f < 4; ++f)
                        acc[i][f] = __builtin_amdgcn_mfma_f32_32x32x16_bf16(
                            a[s][i], bfr[s][f], acc[i][f], 0, 0, 0);
        }

        // group boundary: next group's W (and any restaged x) must be visible.
        // DMA was issued a full group ago -> drain is ~free.
        if (grp + 1 < GROUPS) {
            __builtin_amdgcn_sched_barrier(0);
            asm volatile("s_waitcnt vmcnt(0) lgkmcnt(0)" ::: "memory");
            __builtin_amdgcn_sched_barrier(0);
            __builtin_amdgcn_s_barrier();
            __builtin_amdgcn_sched_barrier(0);
        }
    }

    // epilogue: 32x32 C/D: col=lane&31 (pixel w), row=(reg&3)+8*(reg>>2)+4*(lane>>5) (co)
    float* op = out + (size_t)b * kCOUT * HW;
    #pragma unroll
    for (int i = 0; i < 4; ++i) {
        #pragma unroll
        for (int rg = 0; rg < 16; ++rg) {
            int co = cog + i * 32 + (rg & 3) + 8 * (rg >> 2) + 4 * hi2;
            float bv = bias[co];
            #pragma unroll
            for (int f = 0; f < 4; ++f) {
                int h = h0 + wrow0 + (f >> 1);
                int wcol = (f & 1) * 32 + l31;
                op[((size_t)co * kH + h) * kW + wcol] = acc[i][f][rg] + bv;
            }
        }
    }
}

extern "C" void kernel_launch(void* const* d_in, const int* in_sizes, int n_in,
                              void* d_out, int out_size, void* d_ws, size_t ws_size,
                              hipStream_t stream) {
    const float* x    = (const float*)d_in[0];
    const float* wsrc = (const float*)d_in[1];
    const float* bias = (const float*)d_in[2];
    float* out = (float*)d_out;
    unsigned short* wt2 = (unsigned short*)d_ws;  // 9*256*256*2 = 1.18 MB scratch

    hipLaunchKernelGGL(wt_transform_kernel, dim3((9 * 256 * 256 + 255) / 256),
                       dim3(256), 0, stream, wsrc, wt2);

    hipLaunchKernelGGL(conv3x3_mfma_kernel, dim3(32 * (kH / ROWS)), dim3(BDIM),
                       0, stream, x, wt2, bias, out);
}

// Round 12
// 253.133 us; speedup vs baseline: 1.0407x; 1.0407x over previous
//
#include <hip/hip_runtime.h>
#include <hip/hip_bf16.h>

typedef __attribute__((ext_vector_type(8))) short short8;
typedef __attribute__((ext_vector_type(16))) float floatx16;

#define BDIM 256

constexpr int kCIN = 256, kCOUT = 256, kH = 64, kW = 64;
constexpr int BK = 32;                  // ci per chunk
constexpr int NCHUNK = kCIN / BK;       // 8
constexpr int ROWS = 4;                 // output rows per block
constexpr int XR = ROWS + 2, XC = 66, NPIX = XR * XC;  // 396 halo pixels
constexpr int HW = kH * kW;
constexpr int GROUPS = NCHUNK * 3;      // 24 (group = one kh row of taps)

// K-major LDS layouts (contiguous per 32-lane half => conflict-free):
//   xs: [buf2][g=0..3][pix][16B]   ws: [buf2][tap j=0..2][g=0..3][co][16B]
constexpr int XS_PLANE = NPIX * 16;
constexpr int XS_BUF   = 4 * XS_PLANE;   // 25.3 KB
constexpr int WS_PLANE = 256 * 16;
constexpr int WS_TILE  = 4 * WS_PLANE;   // 16 KB
constexpr int WS_GRP   = 3 * WS_TILE;    // 48 KB
// total LDS 145.5 KB -> 1 block/CU, 1 wave/SIMD (ILP regime)

__device__ __forceinline__ unsigned short f2bf(float f) {
    unsigned u = __float_as_uint(f);
    u += 0x7fffu + ((u >> 16) & 1u);   // RNE
    return (unsigned short)(u >> 16);
}

// weight[co][ci][kh][kw] fp32 -> wt2[kk][chunk][g][co][j] bf16 (ci=chunk*32+g*8+j)
__global__ void wt_transform_kernel(const float* __restrict__ wsrc,
                                    unsigned short* __restrict__ wt2) {
    int idx = blockIdx.x * 256 + threadIdx.x;
    if (idx >= 9 * 256 * 256) return;
    int j  = idx & 7;
    int co = (idx >> 3) & 255;
    int g  = (idx >> 11) & 3;
    int chunk = (idx >> 13) & 7;
    int kk = idx >> 16;
    int ci = chunk * 32 + g * 8 + j;
    wt2[idx] = f2bf(wsrc[(co * 256 + ci) * 9 + kk]);
}

struct Frags { short8 a[2][4]; short8 b[2][4]; };

// Block: 256 cout x 256 pixels (4 rows). 4 waves = 2(co-group) x 2(row-pair).
// Wave tile: 128 co x 128 pix -> acc 4x4 frags (256 regs); 16 ds_reads feed
// 32 MFMAs per tap (0.5 reads/MFMA). Explicit 2-deep fragment pipeline +
// lean lane->column stageX (no div/mod, no big temporaries: R11's spill fix).
__global__ __launch_bounds__(BDIM, 1)
void conv3x3_mfma_kernel(const float* __restrict__ x,
                         const unsigned short* __restrict__ wt2,
                         const float* __restrict__ bias,
                         float* __restrict__ out) {
    __shared__ __align__(16) char xs[2 * XS_BUF];   // 50.7 KB
    __shared__ __align__(16) char ws[2 * WS_GRP];   // 96 KB

    const int bid = blockIdx.x;
    const int b  = bid >> 4;            // 16 h-tiles per image
    const int h0 = (bid & 15) * ROWS;

    const int tid = threadIdx.x;
    const int wv  = tid >> 6;           // 0..3
    const int l   = tid & 63;
    const int l31 = l & 31;
    const int hi2 = l >> 5;
    const int cog   = (wv & 1) * 128;   // wave's cout base (0/128)
    const int wrow0 = (wv >> 1) * 2;    // wave's first output row (0/2)

    const float* xb = x + (size_t)b * kCIN * HW;

    floatx16 acc[4][4] = {};            // [co frag][pix frag]

    // Stage the 3 W tiles of group grp into buf grp&1 (12 DMA calls/wave).
    auto stageW3 = [&](int grp) {
        int chunk = grp / 3, kh = grp % 3;
        char* gbuf = ws + (grp & 1) * WS_GRP;
        #pragma unroll
        for (int j = 0; j < 3; ++j) {
            int kk = kh * 3 + j;
            const unsigned short* wp = wt2 + (size_t)(kk * 8 + chunk) * 8192;
            char* wbuf = gbuf + j * WS_TILE;
            #pragma unroll
            for (int it = 0; it < 4; ++it) {
                int c = wv * 4 + it;     // 0..15
                int g = c >> 2;
                int row0 = (c & 3) * 64;
                const unsigned short* src = wp + (g * 256 + row0 + l) * 8;
                __builtin_amdgcn_global_load_lds(
                    (const __attribute__((address_space(1))) unsigned int*)src,
                    (__attribute__((address_space(3))) unsigned int*)
                        (wbuf + g * WS_PLANE + row0 * 16),
                    16, 0, 0);
            }
        }
    };

    // Lean x staging: 24 wave-tasks (g,r), lane -> column iw=l. Pad columns
    // (c=0,65) and out-of-image rows pre-zeroed once; only interior re-staged.
    auto stageX = [&](int chunk) {
        char* xbuf = xs + (chunk & 1) * XS_BUF;
        const int ci0 = chunk * BK;
        #pragma unroll
        for (int it = 0; it < 6; ++it) {
            int c = wv * 6 + it;         // 0..23
            int r = c >> 2;              // 0..5
            int g = c & 3;
            int ih = h0 - 1 + r;
            if ((unsigned)ih < (unsigned)kH) {
                const float* p = xb + (size_t)(ci0 + g * 8) * HW + ih * kW + l;
                union { short8 s8; unsigned short u[8]; } pk;
                #pragma unroll
                for (int j = 0; j < 8; ++j) pk.u[j] = f2bf(p[(size_t)j * HW]);
                *(short8*)(xbuf + g * XS_PLANE + (r * XC + 1 + l) * 16) = pk.s8;
            }
        }
    };

    auto loadF = [&](const char* gbuf, const char* xbuf, int kh, int kwo,
                     Frags& F) {
        const char* wbuf = gbuf + kwo * WS_TILE;
        #pragma unroll
        for (int s = 0; s < 2; ++s) {
            const int g = s * 2 + hi2;
            #pragma unroll
            for (int i = 0; i < 4; ++i) {
                int co = cog + i * 32 + l31;
                F.a[s][i] = *(const short8*)(wbuf + g * WS_PLANE + co * 16);
            }
            #pragma unroll
            for (int f = 0; f < 4; ++f) {
                int r = wrow0 + (f >> 1) + kh;
                int pix = r * XC + (f & 1) * 32 + l31 + kwo;
                F.b[s][f] = *(const short8*)(xbuf + g * XS_PLANE + pix * 16);
            }
        }
    };

    auto mfma32 = [&](const Frags& F) {
        #pragma unroll
        for (int s = 0; s < 2; ++s)
            #pragma unroll
            for (int i = 0; i < 4; ++i)
                #pragma unroll
                for (int f = 0; f < 4; ++f)
                    acc[i][f] = __builtin_amdgcn_mfma_f32_32x32x16_bf16(
                        F.a[s][i], F.b[s][f], acc[i][f], 0, 0, 0);
    };

    // prologue: zero both xs buffers (pad cols + boundary rows stay zero)
    {
        short8 z = {};
        for (int i = tid; i < 2 * XS_BUF / 16; i += BDIM)
            *(short8*)(xs + i * 16) = z;
    }
    __syncthreads();
    stageX(0);
    stageW3(0);
    __syncthreads();                    // prologue drain (once)

    #pragma unroll 1
    for (int grp = 0; grp < GROUPS; ++grp) {
        const int chunk = grp / 3;
        const int kh = grp % 3;

        if (grp + 1 < GROUPS) stageW3(grp + 1);   // fire-and-forget DMA

        const char* gbuf = ws + (grp & 1) * WS_GRP;
        const char* xbuf = xs + (chunk & 1) * XS_BUF;

        Frags fA, fB;
        loadF(gbuf, xbuf, kh, 0, fA);
        loadF(gbuf, xbuf, kh, 1, fB);
        mfma32(fA);
        loadF(gbuf, xbuf, kh, 2, fA);
        mfma32(fB);
        mfma32(fA);

        // x restage for next chunk: issued after the MFMA burst so its global
        // loads hide under the matrix pipe; ds_writes drain at the barrier.
        if (kh == 0 && chunk + 1 < NCHUNK) stageX(chunk + 1);

        if (grp + 1 < GROUPS) {
            __builtin_amdgcn_sched_barrier(0);
            asm volatile("s_waitcnt vmcnt(0) lgkmcnt(0)" ::: "memory");
            __builtin_amdgcn_sched_barrier(0);
            __builtin_amdgcn_s_barrier();
            __builtin_amdgcn_sched_barrier(0);
        }
    }

    // epilogue: 32x32 C/D: col=lane&31 (pixel w), row=(reg&3)+8*(reg>>2)+4*(lane>>5) (co)
    float* op = out + (size_t)b * kCOUT * HW;
    #pragma unroll
    for (int i = 0; i < 4; ++i) {
        #pragma unroll
        for (int rg = 0; rg < 16; ++rg) {
            int co = cog + i * 32 + (rg & 3) + 8 * (rg >> 2) + 4 * hi2;
            float bv = bias[co];
            #pragma unroll
            for (int f = 0; f < 4; ++f) {
                int h = h0 + wrow0 + (f >> 1);
                int wcol = (f & 1) * 32 + l31;
                op[((size_t)co * kH + h) * kW + wcol] = acc[i][f][rg] + bv;
            }
        }
    }
}

extern "C" void kernel_launch(void* const* d_in, const int* in_sizes, int n_in,
                              void* d_out, int out_size, void* d_ws, size_t ws_size,
                              hipStream_t stream) {
    const float* x    = (const float*)d_in[0];
    const float* wsrc = (const float*)d_in[1];
    const float* bias = (const float*)d_in[2];
    float* out = (float*)d_out;
    unsigned short* wt2 = (unsigned short*)d_ws;  // 9*256*256*2 = 1.18 MB scratch

    hipLaunchKernelGGL(wt_transform_kernel, dim3((9 * 256 * 256 + 255) / 256),
                       dim3(256), 0, stream, wsrc, wt2);

    hipLaunchKernelGGL(conv3x3_mfma_kernel, dim3(32 * (kH / ROWS)), dim3(BDIM),
                       0, stream, x, wt2, bias, out);
}